// Round 5
// baseline (2082.332 us; speedup 1.0000x reference)
//
#include <hip/hip_runtime.h>
#include <hip/hip_bf16.h>
#include <math.h>

#define NB 512              // persistent blocks (2 per CU on 256 CUs -> guaranteed co-resident)
#define NT 256
#define NWAVES (NB * 4)
#define N_NODES 10000
#define N_EDGES 160000

typedef __attribute__((ext_vector_type(8))) short bf16x8;
typedef __attribute__((ext_vector_type(4))) float f32x4;

static __device__ inline unsigned short f2b(float v) {
    __hip_bfloat16 b = __float2bfloat16(v);
    return *reinterpret_cast<unsigned short*>(&b);
}

struct Params {
    const float* x0; const int* ei; const float* ea;
    const float* w1[3]; const float* b1[3];
    const float* w2[3]; const float* b2[3];
    const float* root[3]; const float* bias[3];
    const float* fcw; const float* fcb;
    float* out;
    int* bar; int* gen;
    int* cnt_src; int* cnt_dst; int* cur_src; int* cur_dst;
    int* off_src; int* off_dst; int* perm;
    float* w2t0; float* w2t1; float* w2t2;
    float* aggA; float* aggB; float* msgf;
    unsigned short* h0; unsigned short* h1; unsigned short* h2;
};

// ---- device-wide sense-reversing barrier (all NB blocks co-resident) ----
static __device__ inline void gbar(int* bar, int* gen) {
    __threadfence();
    __syncthreads();
    if (threadIdx.x == 0) {
        int g = __hip_atomic_load(gen, __ATOMIC_RELAXED, __HIP_MEMORY_SCOPE_AGENT);
        if (__hip_atomic_fetch_add(bar, 1, __ATOMIC_ACQ_REL, __HIP_MEMORY_SCOPE_AGENT) == NB - 1) {
            __hip_atomic_store(bar, 0, __ATOMIC_RELAXED, __HIP_MEMORY_SCOPE_AGENT);
            __hip_atomic_fetch_add(gen, 1, __ATOMIC_RELEASE, __HIP_MEMORY_SCOPE_AGENT);
        } else {
            while (__hip_atomic_load(gen, __ATOMIC_ACQUIRE, __HIP_MEMORY_SCOPE_AGENT) == g)
                __builtin_amdgcn_s_sleep(8);
        }
    }
    __syncthreads();
}

// ---- per-src-node edge phase: build MFMA B-frags of G_n in regs, stream edges ----
template <int DIN>
static __device__ void edge_phase(const float* __restrict__ xin,   // [N,DIN] (already relu'd when needed)
                                  const float* __restrict__ w2t,   // [DIN,1024]: w2t[i*1024 + o*32 + k]
                                  const float* __restrict__ b2,    // [DIN*32]
                                  const unsigned short* __restrict__ hb,
                                  const Params& P) {
    const int t = threadIdx.x;
    const int lane = t & 63;
    const int col = lane & 15;
    const int quad = lane >> 4;
    const int q8 = quad * 8;
    const int w = blockIdx.x * 4 + (t >> 6);

    for (int n = w; n < N_NODES; n += NWAVES) {
        float xv[DIN];
#pragma unroll
        for (int i = 0; i < DIN; i += 4) {
            float4 v = *(const float4*)(xin + (size_t)n * DIN + i);
            xv[i] = v.x; xv[i + 1] = v.y; xv[i + 2] = v.z; xv[i + 3] = v.w;
        }
        float alo[8] = {0, 0, 0, 0, 0, 0, 0, 0};
        float ahi[8] = {0, 0, 0, 0, 0, 0, 0, 0};
        float xb_lo = 0.f, xb_hi = 0.f;
#pragma unroll
        for (int i = 0; i < DIN; ++i) {
            const float* wrow = w2t + i * 1024;
            float4 wl0 = *(const float4*)(wrow + col * 32 + q8);
            float4 wl1 = *(const float4*)(wrow + col * 32 + q8 + 4);
            float4 wh0 = *(const float4*)(wrow + (col + 16) * 32 + q8);
            float4 wh1 = *(const float4*)(wrow + (col + 16) * 32 + q8 + 4);
            float x = xv[i];
            alo[0] += x * wl0.x; alo[1] += x * wl0.y; alo[2] += x * wl0.z; alo[3] += x * wl0.w;
            alo[4] += x * wl1.x; alo[5] += x * wl1.y; alo[6] += x * wl1.z; alo[7] += x * wl1.w;
            ahi[0] += x * wh0.x; ahi[1] += x * wh0.y; ahi[2] += x * wh0.z; ahi[3] += x * wh0.w;
            ahi[4] += x * wh1.x; ahi[5] += x * wh1.y; ahi[6] += x * wh1.z; ahi[7] += x * wh1.w;
            xb_lo += x * b2[i * 32 + col];
            xb_hi += x * b2[i * 32 + 16 + col];
        }
        bf16x8 b_lo, b_hi;
#pragma unroll
        for (int j = 0; j < 8; ++j) {
            b_lo[j] = (short)f2b(alo[j]);
            b_hi[j] = (short)f2b(ahi[j]);
        }

        int jb = P.off_src[n], je = P.off_src[n + 1];
        for (int e0 = jb; e0 < je; e0 += 16) {
            int eA = e0 + col;
            bf16x8 afrag = {0, 0, 0, 0, 0, 0, 0, 0};
            if (eA < je) afrag = *(const bf16x8*)(hb + (size_t)eA * 32 + q8);
            f32x4 acc_lo = {xb_lo, xb_lo, xb_lo, xb_lo};
            f32x4 acc_hi = {xb_hi, xb_hi, xb_hi, xb_hi};
            acc_lo = __builtin_amdgcn_mfma_f32_16x16x32_bf16(afrag, b_lo, acc_lo, 0, 0, 0);
            acc_hi = __builtin_amdgcn_mfma_f32_16x16x32_bf16(afrag, b_hi, acc_hi, 0, 0, 0);
#pragma unroll
            for (int r = 0; r < 4; ++r) {
                int er = e0 + quad * 4 + r;
                if (er < je) {
                    size_t p = (size_t)P.perm[er] * 32;
                    P.msgf[p + col] = acc_lo[r];
                    P.msgf[p + 16 + col] = acc_hi[r];
                }
            }
        }
    }
}

// ---- per-dst-node aggregation (+ optional fused head) ----
template <int DIN, bool HEAD>
static __device__ void agg_phase(const float* __restrict__ xin,   // layer input for root term
                                 const float* __restrict__ root,  // [DIN,32]
                                 const float* __restrict__ bias,  // [32]
                                 const Params& P,
                                 float* __restrict__ aggout) {
    const int t = threadIdx.x;
    const int o = t & 31;
    for (int n = blockIdx.x * 8 + (t >> 5); n < N_NODES; n += NB * 8) {
        float s = bias[o];
#pragma unroll
        for (int i = 0; i < DIN; ++i)
            s += xin[(size_t)n * DIN + i] * root[i * 32 + o];
        int jb = P.off_dst[n], je = P.off_dst[n + 1];
        for (int j = jb; j < je; ++j)
            s += P.msgf[(size_t)j * 32 + o];
        float a = fmaxf(s, 0.f);
        if (!HEAD) {
            aggout[(size_t)n * 32 + o] = a;   // stored pre-relu'd for next layer
        } else {
            float4 p;
            p.x = a * P.fcw[o * 4 + 0];
            p.y = a * P.fcw[o * 4 + 1];
            p.z = a * P.fcw[o * 4 + 2];
            p.w = a * P.fcw[o * 4 + 3];
#pragma unroll
            for (int m = 16; m >= 1; m >>= 1) {
                p.x += __shfl_xor(p.x, m, 32);
                p.y += __shfl_xor(p.y, m, 32);
                p.z += __shfl_xor(p.z, m, 32);
                p.w += __shfl_xor(p.w, m, 32);
            }
            if (o == 0) {
                float l0 = p.x + P.fcb[0], l1 = p.y + P.fcb[1];
                float l2 = p.z + P.fcb[2], l3 = p.w + P.fcb[3];
                float mx = fmaxf(fmaxf(l0, l1), fmaxf(l2, l3));
                float sm = expf(l0 - mx) + expf(l1 - mx) + expf(l2 - mx) + expf(l3 - mx);
                float lse = mx + logf(sm);
                *(float4*)(P.out + (size_t)n * 4) =
                    make_float4(l0 - lse, l1 - lse, l2 - lse, l3 - lse);
            }
        }
    }
}

// ---- init: zero barrier state + histograms (single block, runs before k_main) ----
__global__ __launch_bounds__(256) void k_init(int* z) {
    for (int d = threadIdx.x; d < 64 + 2 * 10240; d += 256) z[d] = 0;
}

// ---- the megakernel ----
__global__ __launch_bounds__(NT, 2) void k_main(Params P) {
    const int t = threadIdx.x;
    const int gtid = blockIdx.x * NT + t;

    // P0: transpose w2 -> w2t (fp32): w2t[i*1024 + o*32 + k] = w2[k*(din*32) + i*32 + o]
    for (int d = gtid; d < 4096 + 32768 + 32768; d += NB * NT) {
        if (d < 4096) {
            int i = d >> 10, j = d & 1023, o = j >> 5, k = j & 31;
            P.w2t0[d] = P.w2[0][k * 128 + i * 32 + o];
        } else if (d < 4096 + 32768) {
            int q = d - 4096;
            int i = q >> 10, j = q & 1023, o = j >> 5, k = j & 31;
            P.w2t1[q] = P.w2[1][k * 1024 + i * 32 + o];
        } else {
            int q = d - 4096 - 32768;
            int i = q >> 10, j = q & 1023, o = j >> 5, k = j & 31;
            P.w2t2[q] = P.w2[2][k * 1024 + i * 32 + o];
        }
    }
    gbar(P.bar, P.gen);

    // P1: histograms
    for (int e = gtid; e < N_EDGES; e += NB * NT) {
        atomicAdd(&P.cnt_src[P.ei[e]], 1);
        atomicAdd(&P.cnt_dst[P.ei[N_EDGES + e]], 1);
    }
    gbar(P.bar, P.gen);

    // P2: two-block exclusive scans
    {
        __shared__ int part[256];
        if (blockIdx.x < 2) {
            const int* cnt = blockIdx.x == 0 ? P.cnt_src : P.cnt_dst;
            int* off = blockIdx.x == 0 ? P.off_src : P.off_dst;
            int* cur = blockIdx.x == 0 ? P.cur_src : P.cur_dst;
            int base = t * 40;
            int s = 0;
            for (int i = 0; i < 40; ++i) {
                int idx = base + i;
                if (idx < N_NODES) s += cnt[idx];
            }
            part[t] = s;
            __syncthreads();
            for (int d = 1; d < 256; d <<= 1) {
                int v = (t >= d) ? part[t - d] : 0;
                __syncthreads();
                part[t] += v;
                __syncthreads();
            }
            int run = part[t] - s;
            for (int i = 0; i < 40; ++i) {
                int idx = base + i;
                if (idx < N_NODES) {
                    off[idx] = run;
                    cur[idx] = run;
                    run += cnt[idx];
                }
            }
            if (t == 255) off[N_NODES] = run;
        }
    }
    gbar(P.bar, P.gen);

    // P3: scatter edges into src-sorted order, build dst perm, compute h for all 3 layers
    for (int e = gtid; e < N_EDGES; e += NB * NT) {
        float a0 = P.ea[2 * e], a1 = P.ea[2 * e + 1];
        int src = P.ei[e], dst = P.ei[N_EDGES + e];
        int pos = atomicAdd(&P.cur_src[src], 1);
        P.perm[pos] = atomicAdd(&P.cur_dst[dst], 1);
        unsigned short* H[3] = {P.h0, P.h1, P.h2};
#pragma unroll
        for (int l = 0; l < 3; ++l) {
            const float* w1 = P.w1[l];
            const float* b1 = P.b1[l];
            unsigned int pk[16];
#pragma unroll
            for (int j = 0; j < 16; ++j) {
                float v0 = fmaxf(a0 * w1[2 * j]     + a1 * w1[32 + 2 * j]     + b1[2 * j],     0.f);
                float v1 = fmaxf(a0 * w1[2 * j + 1] + a1 * w1[32 + 2 * j + 1] + b1[2 * j + 1], 0.f);
                pk[j] = (unsigned int)f2b(v0) | ((unsigned int)f2b(v1) << 16);
            }
            uint4* dp = (uint4*)(H[l] + (size_t)pos * 32);
            dp[0] = make_uint4(pk[0], pk[1], pk[2], pk[3]);
            dp[1] = make_uint4(pk[4], pk[5], pk[6], pk[7]);
            dp[2] = make_uint4(pk[8], pk[9], pk[10], pk[11]);
            dp[3] = make_uint4(pk[12], pk[13], pk[14], pk[15]);
        }
    }
    gbar(P.bar, P.gen);

    // layer 0
    edge_phase<4>(P.x0, P.w2t0, P.b2[0], P.h0, P);
    gbar(P.bar, P.gen);
    agg_phase<4, false>(P.x0, P.root[0], P.bias[0], P, P.aggA);
    gbar(P.bar, P.gen);

    // layer 1
    edge_phase<32>(P.aggA, P.w2t1, P.b2[1], P.h1, P);
    gbar(P.bar, P.gen);
    agg_phase<32, false>(P.aggA, P.root[1], P.bias[1], P, P.aggB);
    gbar(P.bar, P.gen);

    // layer 2 + fused head
    edge_phase<32>(P.aggB, P.w2t2, P.b2[2], P.h2, P);
    gbar(P.bar, P.gen);
    agg_phase<32, true>(P.aggB, P.root[2], P.bias[2], P, nullptr);
}

extern "C" void kernel_launch(void* const* d_in, const int* in_sizes, int n_in,
                              void* d_out, int out_size, void* d_ws, size_t ws_size,
                              hipStream_t stream) {
    Params P;
    P.x0 = (const float*)d_in[0];
    P.ei = (const int*)d_in[1];
    P.ea = (const float*)d_in[2];
    for (int l = 0; l < 3; ++l) {
        P.w1[l]   = (const float*)d_in[3 + 6 * l];
        P.b1[l]   = (const float*)d_in[4 + 6 * l];
        P.w2[l]   = (const float*)d_in[5 + 6 * l];
        P.b2[l]   = (const float*)d_in[6 + 6 * l];
        P.root[l] = (const float*)d_in[7 + 6 * l];
        P.bias[l] = (const float*)d_in[8 + 6 * l];
    }
    P.fcw = (const float*)d_in[21];
    P.fcb = (const float*)d_in[22];
    P.out = (float*)d_out;

    // ---- workspace layout ----
    int* base = (int*)d_ws;
    P.bar = base;                 // [0]
    P.gen = base + 32;            // [32]  (separate cache line)
    int o = 64;
    P.cnt_src = base + o; o += 10240;
    P.cnt_dst = base + o; o += 10240;
    P.cur_src = base + o; o += 10240;
    P.cur_dst = base + o; o += 10240;
    P.off_src = base + o; o += 10240;
    P.off_dst = base + o; o += 10240;
    P.perm    = base + o; o += 163840;
    float* f = (float*)(base + o);
    P.w2t0 = f; f += 4096;
    P.w2t1 = f; f += 32768;
    P.w2t2 = f; f += 32768;
    P.aggA = f; f += 320000;
    P.aggB = f; f += 320000;
    P.msgf = f; f += 5120000;
    P.h0 = (unsigned short*)f;
    P.h1 = P.h0 + 5120000;
    P.h2 = P.h1 + 5120000;

    k_init<<<1, 256, 0, stream>>>(base);   // zeros bar/gen + cnt_src + cnt_dst
    k_main<<<NB, NT, 0, stream>>>(P);
}

// Round 6
// 546.804 us; speedup vs baseline: 3.8082x; 3.8082x over previous
//
#include <hip/hip_runtime.h>
#include <hip/hip_bf16.h>
#include <math.h>

#define N_NODES 10000
#define N_EDGES 160000

typedef __attribute__((ext_vector_type(8))) short bf16x8;
typedef __attribute__((ext_vector_type(4))) float f32x4;

static __device__ inline unsigned short f2b(float v) {
    __hip_bfloat16 b = __float2bfloat16(v);
    return *reinterpret_cast<unsigned short*>(&b);
}

// ---------- zero cnt_src/cnt_dst + transpose all three w2 ----------
// w2t[i*1024 + o*32 + k] = w2[k*(din*32) + i*32 + o]
__global__ __launch_bounds__(256) void k_pre0(const float* __restrict__ s0,
                                              const float* __restrict__ s1,
                                              const float* __restrict__ s2,
                                              float* __restrict__ t0,
                                              float* __restrict__ t1,
                                              float* __restrict__ t2,
                                              int* __restrict__ cnt2) {  // cnt_src|cnt_dst, 20480 ints
    int tid = blockIdx.x * 256 + threadIdx.x;
    if (tid < 20480) { cnt2[tid] = 0; return; }
    int d = tid - 20480;
    if (d < 4096) {                            // layer 0, din=4
        int i = d >> 10, j = d & 1023, o = j >> 5, k = j & 31;
        t0[d] = s0[k * 128 + i * 32 + o];
    } else if (d < 4096 + 32768) {
        int q = d - 4096;
        int i = q >> 10, j = q & 1023, o = j >> 5, k = j & 31;
        t1[q] = s1[k * 1024 + i * 32 + o];
    } else if (d < 4096 + 65536) {
        int q = d - 4096 - 32768;
        int i = q >> 10, j = q & 1023, o = j >> 5, k = j & 31;
        t2[q] = s2[k * 1024 + i * 32 + o];
    }
}

// ---------- histograms for both src and dst ----------
__global__ __launch_bounds__(256) void k_hist(const int* __restrict__ ei,
                                              int* __restrict__ cnt_src,
                                              int* __restrict__ cnt_dst) {
    int e = blockIdx.x * 256 + threadIdx.x;
    if (e >= N_EDGES) return;
    atomicAdd(&cnt_src[ei[e]], 1);
    atomicAdd(&cnt_dst[ei[N_EDGES + e]], 1);
}

// grid=2: block 0 scans src counts, block 1 scans dst counts
__global__ __launch_bounds__(256) void k_scan(const int* __restrict__ cnt_src,
                                              const int* __restrict__ cnt_dst,
                                              int* __restrict__ off_src,
                                              int* __restrict__ off_dst,
                                              int* __restrict__ cur_src,
                                              int* __restrict__ cur_dst) {
    const int* cnt = blockIdx.x == 0 ? cnt_src : cnt_dst;
    int* off = blockIdx.x == 0 ? off_src : off_dst;
    int* cur = blockIdx.x == 0 ? cur_src : cur_dst;
    __shared__ int part[256];
    int t = threadIdx.x;
    int base = t * 40;
    int s = 0;
    for (int i = 0; i < 40; ++i) {
        int idx = base + i;
        if (idx < N_NODES) s += cnt[idx];
    }
    part[t] = s;
    __syncthreads();
    for (int d = 1; d < 256; d <<= 1) {
        int v = (t >= d) ? part[t - d] : 0;
        __syncthreads();
        part[t] += v;
        __syncthreads();
    }
    int run = part[t] - s;
    for (int i = 0; i < 40; ++i) {
        int idx = base + i;
        if (idx < N_NODES) {
            off[idx] = run;
            cur[idx] = run;
            run += cnt[idx];
        }
    }
    if (t == 255) off[N_NODES] = run;
}

// ---------- scatter edges into src-sorted order, build dst-perm, compute h (3 layers, bf16) ----------
__global__ __launch_bounds__(256) void k_scatter_h(const int* __restrict__ ei,
                                                   const float* __restrict__ ea,
                                                   int* __restrict__ cur_src,
                                                   int* __restrict__ cur_dst,
                                                   int* __restrict__ perm,   // src-sorted pos -> dst-sorted pos
                                                   const float* __restrict__ w1a, const float* __restrict__ b1a,
                                                   const float* __restrict__ w1b, const float* __restrict__ b1b,
                                                   const float* __restrict__ w1c, const float* __restrict__ b1c,
                                                   unsigned short* __restrict__ h0,
                                                   unsigned short* __restrict__ h1,
                                                   unsigned short* __restrict__ h2) {
    int e = blockIdx.x * 256 + threadIdx.x;
    if (e >= N_EDGES) return;
    float a0 = ea[2 * e], a1 = ea[2 * e + 1];
    int src = ei[e], dst = ei[N_EDGES + e];
    int pos = atomicAdd(&cur_src[src], 1);
    perm[pos] = atomicAdd(&cur_dst[dst], 1);
    const float* W1[3] = {w1a, w1b, w1c};
    const float* B1[3] = {b1a, b1b, b1c};
    unsigned short* H[3] = {h0, h1, h2};
#pragma unroll
    for (int l = 0; l < 3; ++l) {
        unsigned int pk[16];
#pragma unroll
        for (int j = 0; j < 16; ++j) {
            float v0 = fmaxf(a0 * W1[l][2 * j]     + a1 * W1[l][32 + 2 * j]     + B1[l][2 * j],     0.f);
            float v1 = fmaxf(a0 * W1[l][2 * j + 1] + a1 * W1[l][32 + 2 * j + 1] + B1[l][2 * j + 1], 0.f);
            pk[j] = (unsigned int)f2b(v0) | ((unsigned int)f2b(v1) << 16);
        }
        uint4* dp = (uint4*)(H[l] + (size_t)pos * 32);
        dp[0] = make_uint4(pk[0], pk[1], pk[2], pk[3]);
        dp[1] = make_uint4(pk[4], pk[5], pk[6], pk[7]);
        dp[2] = make_uint4(pk[8], pk[9], pk[10], pk[11]);
        dp[3] = make_uint4(pk[12], pk[13], pk[14], pk[15]);
    }
}

// ---------- fused edge kernel: one wave per src node ----------
// Builds G_n B-frags + xb2 in registers from w2t/xin, then MFMA over the node's
// src-sorted edge tiles, storing msg rows to dst-sorted positions (no atomics).
template <int DIN>
__global__ __launch_bounds__(256) void k_edge(const float* __restrict__ xin,  // [N,DIN] (post-relu for l>0)
                                              const float* __restrict__ w2t,  // [DIN,1024]: w2t[i*1024+o*32+k]
                                              const float* __restrict__ b2,   // [DIN*32]
                                              const int* __restrict__ off_src,
                                              const int* __restrict__ perm,
                                              const unsigned short* __restrict__ hb,
                                              float* __restrict__ msgf) {
    const int t = threadIdx.x;
    const int lane = t & 63;
    const int col = lane & 15;
    const int quad = lane >> 4;
    const int q8 = quad * 8;
    const int n = blockIdx.x * 4 + (t >> 6);   // exactly 10000 waves

    float xv[DIN];
#pragma unroll
    for (int i = 0; i < DIN; i += 4) {
        float4 v = *(const float4*)(xin + (size_t)n * DIN + i);
        xv[i] = v.x; xv[i + 1] = v.y; xv[i + 2] = v.z; xv[i + 3] = v.w;
    }
    float alo[8] = {0, 0, 0, 0, 0, 0, 0, 0};
    float ahi[8] = {0, 0, 0, 0, 0, 0, 0, 0};
    float xb_lo = 0.f, xb_hi = 0.f;
#pragma unroll
    for (int i = 0; i < DIN; ++i) {
        const float* wrow = w2t + i * 1024;
        float4 wl0 = *(const float4*)(wrow + col * 32 + q8);
        float4 wl1 = *(const float4*)(wrow + col * 32 + q8 + 4);
        float4 wh0 = *(const float4*)(wrow + (col + 16) * 32 + q8);
        float4 wh1 = *(const float4*)(wrow + (col + 16) * 32 + q8 + 4);
        float x = xv[i];
        alo[0] += x * wl0.x; alo[1] += x * wl0.y; alo[2] += x * wl0.z; alo[3] += x * wl0.w;
        alo[4] += x * wl1.x; alo[5] += x * wl1.y; alo[6] += x * wl1.z; alo[7] += x * wl1.w;
        ahi[0] += x * wh0.x; ahi[1] += x * wh0.y; ahi[2] += x * wh0.z; ahi[3] += x * wh0.w;
        ahi[4] += x * wh1.x; ahi[5] += x * wh1.y; ahi[6] += x * wh1.z; ahi[7] += x * wh1.w;
        xb_lo += x * b2[i * 32 + col];
        xb_hi += x * b2[i * 32 + 16 + col];
    }
    bf16x8 b_lo, b_hi;
#pragma unroll
    for (int j = 0; j < 8; ++j) {
        b_lo[j] = (short)f2b(alo[j]);
        b_hi[j] = (short)f2b(ahi[j]);
    }

    int jb = off_src[n], je = off_src[n + 1];
    for (int e0 = jb; e0 < je; e0 += 16) {
        int eA = e0 + col;
        bf16x8 afrag = {0, 0, 0, 0, 0, 0, 0, 0};
        if (eA < je) afrag = *(const bf16x8*)(hb + (size_t)eA * 32 + q8);
        f32x4 acc_lo = {xb_lo, xb_lo, xb_lo, xb_lo};
        f32x4 acc_hi = {xb_hi, xb_hi, xb_hi, xb_hi};
        acc_lo = __builtin_amdgcn_mfma_f32_16x16x32_bf16(afrag, b_lo, acc_lo, 0, 0, 0);
        acc_hi = __builtin_amdgcn_mfma_f32_16x16x32_bf16(afrag, b_hi, acc_hi, 0, 0, 0);
#pragma unroll
        for (int r = 0; r < 4; ++r) {
            int er = e0 + quad * 4 + r;
            if (er < je) {
                size_t p = (size_t)perm[er] * 32;
                msgf[p + col] = acc_lo[r];
                msgf[p + 16 + col] = acc_hi[r];
            }
        }
    }
}

// ---------- fused aggregation: root term + bias + segment-sum + relu (+ head) ----------
template <int DIN, bool HEAD>
__global__ __launch_bounds__(256) void k_agg(const float* __restrict__ xin,   // layer input (for root term)
                                             const float* __restrict__ root,  // [DIN,32]
                                             const float* __restrict__ bias,  // [32]
                                             const int* __restrict__ off_dst,
                                             const float* __restrict__ msgf,
                                             const float* __restrict__ fcw,
                                             const float* __restrict__ fcb,
                                             float* __restrict__ outp) {      // aggout or logits out
    const int t = threadIdx.x;
    const int o = t & 31;
    const int n = blockIdx.x * 8 + (t >> 5);   // exactly 10000
    float s = bias[o];
#pragma unroll
    for (int i = 0; i < DIN; ++i)
        s += xin[(size_t)n * DIN + i] * root[i * 32 + o];
    int jb = off_dst[n], je = off_dst[n + 1];
    for (int j = jb; j < je; ++j)
        s += msgf[(size_t)j * 32 + o];
    float a = fmaxf(s, 0.f);
    if (!HEAD) {
        outp[(size_t)n * 32 + o] = a;          // stored post-relu for next layer
    } else {
        float4 p;
        p.x = a * fcw[o * 4 + 0];
        p.y = a * fcw[o * 4 + 1];
        p.z = a * fcw[o * 4 + 2];
        p.w = a * fcw[o * 4 + 3];
#pragma unroll
        for (int m = 16; m >= 1; m >>= 1) {
            p.x += __shfl_xor(p.x, m, 32);
            p.y += __shfl_xor(p.y, m, 32);
            p.z += __shfl_xor(p.z, m, 32);
            p.w += __shfl_xor(p.w, m, 32);
        }
        if (o == 0) {
            float l0 = p.x + fcb[0], l1 = p.y + fcb[1];
            float l2 = p.z + fcb[2], l3 = p.w + fcb[3];
            float mx = fmaxf(fmaxf(l0, l1), fmaxf(l2, l3));
            float sm = expf(l0 - mx) + expf(l1 - mx) + expf(l2 - mx) + expf(l3 - mx);
            float lse = mx + logf(sm);
            *(float4*)(outp + (size_t)n * 4) =
                make_float4(l0 - lse, l1 - lse, l2 - lse, l3 - lse);
        }
    }
}

extern "C" void kernel_launch(void* const* d_in, const int* in_sizes, int n_in,
                              void* d_out, int out_size, void* d_ws, size_t ws_size,
                              hipStream_t stream) {
    const float* x0 = (const float*)d_in[0];
    const int*   ei = (const int*)d_in[1];
    const float* ea = (const float*)d_in[2];
    const float *W1[3], *B1[3], *W2[3], *B2[3], *RT[3], *BS[3];
    for (int l = 0; l < 3; ++l) {
        W1[l] = (const float*)d_in[3 + 6 * l];
        B1[l] = (const float*)d_in[4 + 6 * l];
        W2[l] = (const float*)d_in[5 + 6 * l];
        B2[l] = (const float*)d_in[6 + 6 * l];
        RT[l] = (const float*)d_in[7 + 6 * l];
        BS[l] = (const float*)d_in[8 + 6 * l];
    }
    const float* fcw = (const float*)d_in[21];
    const float* fcb = (const float*)d_in[22];
    float* out = (float*)d_out;

    // ---- workspace layout ----
    int*   cnt_src = (int*)d_ws;                      // 10240
    int*   cnt_dst = cnt_src + 10240;                 // 10240 (contiguous with cnt_src for zeroing)
    int*   cur_src = cnt_dst + 10240;                 // 10240
    int*   cur_dst = cur_src + 10240;                 // 10240
    int*   off_src = cur_dst + 10240;                 // 10240 (10001 used)
    int*   off_dst = off_src + 10240;                 // 10240 (10001 used)
    int*   perm    = off_dst + 10240;                 // 163840 (160000 used)
    float* w2t0    = (float*)(perm + 163840);         // 4096
    float* w2t1    = w2t0 + 4096;                     // 32768
    float* w2t2    = w2t1 + 32768;                    // 32768
    float* aggA    = w2t2 + 32768;                    // 320000
    float* aggB    = aggA + 320000;                   // 320000
    float* msgf    = aggB + 320000;                   // 5,120,000
    unsigned short* h0 = (unsigned short*)(msgf + 5120000);  // 5,120,000
    unsigned short* h1 = h0 + 5120000;                       // 5,120,000
    unsigned short* h2 = h1 + 5120000;                       // 5,120,000

    const int gE256 = (N_EDGES + 255) / 256;   // 625
    const int gEdge = N_NODES / 4;             // 2500 (1 wave per src node)
    const int gAgg  = N_NODES / 8;             // 1250

    // ---- preprocessing (4 dispatches) ----
    k_pre0<<<352, 256, 0, stream>>>(W2[0], W2[1], W2[2], w2t0, w2t1, w2t2, cnt_src);
    k_hist<<<gE256, 256, 0, stream>>>(ei, cnt_src, cnt_dst);
    k_scan<<<2, 256, 0, stream>>>(cnt_src, cnt_dst, off_src, off_dst, cur_src, cur_dst);
    k_scatter_h<<<gE256, 256, 0, stream>>>(ei, ea, cur_src, cur_dst, perm,
                                           W1[0], B1[0], W1[1], B1[1], W1[2], B1[2],
                                           h0, h1, h2);

    // ---- layer 0 (din=4) ----
    k_edge<4><<<gEdge, 256, 0, stream>>>(x0, w2t0, B2[0], off_src, perm, h0, msgf);
    k_agg<4, false><<<gAgg, 256, 0, stream>>>(x0, RT[0], BS[0], off_dst, msgf, fcw, fcb, aggA);

    // ---- layer 1 (din=32) ----
    k_edge<32><<<gEdge, 256, 0, stream>>>(aggA, w2t1, B2[1], off_src, perm, h1, msgf);
    k_agg<32, false><<<gAgg, 256, 0, stream>>>(aggA, RT[1], BS[1], off_dst, msgf, fcw, fcb, aggB);

    // ---- layer 2 (din=32) + fused head ----
    k_edge<32><<<gEdge, 256, 0, stream>>>(aggB, w2t2, B2[2], off_src, perm, h2, msgf);
    k_agg<32, true><<<gAgg, 256, 0, stream>>>(aggB, RT[2], BS[2], off_dst, msgf, fcw, fcb, out);
}

// Round 7
// 301.820 us; speedup vs baseline: 6.8993x; 1.8117x over previous
//
#include <hip/hip_runtime.h>
#include <hip/hip_bf16.h>
#include <math.h>

#define N_NODES 10000
#define N_EDGES 160000

typedef __attribute__((ext_vector_type(8))) short bf16x8;
typedef __attribute__((ext_vector_type(4))) float f32x4;

static __device__ inline unsigned short f2b(float v) {
    __hip_bfloat16 b = __float2bfloat16(v);
    return *reinterpret_cast<unsigned short*>(&b);
}

// ---------- zero cnt_src/cnt_dst + transpose all three w2 ----------
// w2t[i*1024 + o*32 + k] = w2[k*(din*32) + i*32 + o]
__global__ __launch_bounds__(256) void k_pre0(const float* __restrict__ s0,
                                              const float* __restrict__ s1,
                                              const float* __restrict__ s2,
                                              float* __restrict__ t0,
                                              float* __restrict__ t1,
                                              float* __restrict__ t2,
                                              int* __restrict__ cnt2) {  // cnt_src|cnt_dst, 20480 ints
    int tid = blockIdx.x * 256 + threadIdx.x;
    if (tid < 20480) { cnt2[tid] = 0; return; }
    int d = tid - 20480;
    if (d < 4096) {                            // layer 0, din=4
        int i = d >> 10, j = d & 1023, o = j >> 5, k = j & 31;
        t0[d] = s0[k * 128 + i * 32 + o];
    } else if (d < 4096 + 32768) {
        int q = d - 4096;
        int i = q >> 10, j = q & 1023, o = j >> 5, k = j & 31;
        t1[q] = s1[k * 1024 + i * 32 + o];
    } else if (d < 4096 + 65536) {
        int q = d - 4096 - 32768;
        int i = q >> 10, j = q & 1023, o = j >> 5, k = j & 31;
        t2[q] = s2[k * 1024 + i * 32 + o];
    }
}

// ---------- histograms for both src and dst ----------
__global__ __launch_bounds__(256) void k_hist(const int* __restrict__ ei,
                                              int* __restrict__ cnt_src,
                                              int* __restrict__ cnt_dst) {
    int e = blockIdx.x * 256 + threadIdx.x;
    if (e >= N_EDGES) return;
    atomicAdd(&cnt_src[ei[e]], 1);
    atomicAdd(&cnt_dst[ei[N_EDGES + e]], 1);
}

// grid=2: block 0 scans src counts, block 1 scans dst counts
__global__ __launch_bounds__(256) void k_scan(const int* __restrict__ cnt_src,
                                              const int* __restrict__ cnt_dst,
                                              int* __restrict__ off_src,
                                              int* __restrict__ off_dst,
                                              int* __restrict__ cur_src,
                                              int* __restrict__ cur_dst) {
    const int* cnt = blockIdx.x == 0 ? cnt_src : cnt_dst;
    int* off = blockIdx.x == 0 ? off_src : off_dst;
    int* cur = blockIdx.x == 0 ? cur_src : cur_dst;
    __shared__ int part[256];
    int t = threadIdx.x;
    int base = t * 40;
    int s = 0;
    for (int i = 0; i < 40; ++i) {
        int idx = base + i;
        if (idx < N_NODES) s += cnt[idx];
    }
    part[t] = s;
    __syncthreads();
    for (int d = 1; d < 256; d <<= 1) {
        int v = (t >= d) ? part[t - d] : 0;
        __syncthreads();
        part[t] += v;
        __syncthreads();
    }
    int run = part[t] - s;
    for (int i = 0; i < 40; ++i) {
        int idx = base + i;
        if (idx < N_NODES) {
            off[idx] = run;
            cur[idx] = run;
            run += cnt[idx];
        }
    }
    if (t == 255) off[N_NODES] = run;
}

// ---------- scatter edges into src-sorted order, build dst->src index, compute h (3 layers, bf16) ----------
__global__ __launch_bounds__(256) void k_scatter_h(const int* __restrict__ ei,
                                                   const float* __restrict__ ea,
                                                   int* __restrict__ cur_src,
                                                   int* __restrict__ cur_dst,
                                                   int* __restrict__ idx_dst,  // dst-sorted pos -> src-sorted pos
                                                   const float* __restrict__ w1a, const float* __restrict__ b1a,
                                                   const float* __restrict__ w1b, const float* __restrict__ b1b,
                                                   const float* __restrict__ w1c, const float* __restrict__ b1c,
                                                   unsigned short* __restrict__ h0,
                                                   unsigned short* __restrict__ h1,
                                                   unsigned short* __restrict__ h2) {
    int e = blockIdx.x * 256 + threadIdx.x;
    if (e >= N_EDGES) return;
    float a0 = ea[2 * e], a1 = ea[2 * e + 1];
    int src = ei[e], dst = ei[N_EDGES + e];
    int pos = atomicAdd(&cur_src[src], 1);
    idx_dst[atomicAdd(&cur_dst[dst], 1)] = pos;
    const float* W1[3] = {w1a, w1b, w1c};
    const float* B1[3] = {b1a, b1b, b1c};
    unsigned short* H[3] = {h0, h1, h2};
#pragma unroll
    for (int l = 0; l < 3; ++l) {
        unsigned int pk[16];
#pragma unroll
        for (int j = 0; j < 16; ++j) {
            float v0 = fmaxf(a0 * W1[l][2 * j]     + a1 * W1[l][32 + 2 * j]     + B1[l][2 * j],     0.f);
            float v1 = fmaxf(a0 * W1[l][2 * j + 1] + a1 * W1[l][32 + 2 * j + 1] + B1[l][2 * j + 1], 0.f);
            pk[j] = (unsigned int)f2b(v0) | ((unsigned int)f2b(v1) << 16);
        }
        uint4* dp = (uint4*)(H[l] + (size_t)pos * 32);
        dp[0] = make_uint4(pk[0], pk[1], pk[2], pk[3]);
        dp[1] = make_uint4(pk[4], pk[5], pk[6], pk[7]);
        dp[2] = make_uint4(pk[8], pk[9], pk[10], pk[11]);
        dp[3] = make_uint4(pk[12], pk[13], pk[14], pk[15]);
    }
}

// ---------- G[n, o*32+k] (bf16) = sum_i x[n,i]*w2t[i, o*32+k]; also xb2 (fp32) ----------
template <int DIN>
__global__ __launch_bounds__(256) void k_G(const float* __restrict__ xin,  // [N,DIN], already post-relu
                                           const float* __restrict__ w2t,  // [DIN,1024]
                                           const float* __restrict__ b2,   // [DIN*32]
                                           unsigned short* __restrict__ Gb,
                                           float* __restrict__ xb2) {
    const int t = threadIdx.x;
    const int n0 = blockIdx.x * 16;

    __shared__ float xs[16 * DIN];
    for (int idx = t; idx < 16 * DIN; idx += 256) {
        int m = idx / DIN, i = idx - m * DIN;
        xs[idx] = xin[(size_t)(n0 + m) * DIN + i];
    }
    __syncthreads();

    float acc[16][4];
#pragma unroll
    for (int m = 0; m < 16; ++m)
        acc[m][0] = acc[m][1] = acc[m][2] = acc[m][3] = 0.f;

#pragma unroll
    for (int i = 0; i < DIN; ++i) {
        const float4 w = *(const float4*)(w2t + i * 1024 + t * 4);
#pragma unroll
        for (int m = 0; m < 16; ++m) {
            float xv = xs[m * DIN + i];
            acc[m][0] += xv * w.x;
            acc[m][1] += xv * w.y;
            acc[m][2] += xv * w.z;
            acc[m][3] += xv * w.w;
        }
    }
#pragma unroll
    for (int m = 0; m < 16; ++m) {
        unsigned int p0 = (unsigned int)f2b(acc[m][0]) | ((unsigned int)f2b(acc[m][1]) << 16);
        unsigned int p1 = (unsigned int)f2b(acc[m][2]) | ((unsigned int)f2b(acc[m][3]) << 16);
        *(uint2*)(Gb + (size_t)(n0 + m) * 1024 + t * 4) = make_uint2(p0, p1);
    }

    // xb2[n,o] (512 outputs, 2 per thread)
    for (int idx = t; idx < 512; idx += 256) {
        int m = idx >> 5, o = idx & 31;
        float ab = 0.f;
#pragma unroll
        for (int i = 0; i < DIN; ++i)
            ab += xs[m * DIN + i] * b2[i * 32 + o];
        xb2[(size_t)(n0 + m) * 32 + o] = ab;
    }
}

// ---------- MFMA edge kernel: one wave per src node; CONTIGUOUS stores in src-sorted order ----------
__global__ __launch_bounds__(256) void k_edge(const int* __restrict__ off_src,
                                              const unsigned short* __restrict__ hb,
                                              const unsigned short* __restrict__ Gb,
                                              const float* __restrict__ xb2,
                                              float* __restrict__ msgf) {
    int t = threadIdx.x;
    int lane = t & 63;
    int n = blockIdx.x * 4 + (t >> 6);
    int col = lane & 15;     // C col = o (low half); A row m = edge-in-tile
    int quad = lane >> 4;    // k-block selector
    int q8 = quad * 8;

    // B frags: B[k=quad*8+j][o=col] = G_n[o*32 + k]
    const bf16x8 b_lo = *(const bf16x8*)(Gb + (size_t)n * 1024 + col * 32 + q8);
    const bf16x8 b_hi = *(const bf16x8*)(Gb + (size_t)n * 1024 + (col + 16) * 32 + q8);
    float xb_lo = xb2[(size_t)n * 32 + col];
    float xb_hi = xb2[(size_t)n * 32 + 16 + col];

    int jb = off_src[n], je = off_src[n + 1];
    for (int e0 = jb; e0 < je; e0 += 16) {
        int eA = e0 + col;
        bf16x8 afrag = {0, 0, 0, 0, 0, 0, 0, 0};
        if (eA < je) afrag = *(const bf16x8*)(hb + (size_t)eA * 32 + q8);
        f32x4 acc_lo = {xb_lo, xb_lo, xb_lo, xb_lo};
        f32x4 acc_hi = {xb_hi, xb_hi, xb_hi, xb_hi};
        acc_lo = __builtin_amdgcn_mfma_f32_16x16x32_bf16(afrag, b_lo, acc_lo, 0, 0, 0);
        acc_hi = __builtin_amdgcn_mfma_f32_16x16x32_bf16(afrag, b_hi, acc_hi, 0, 0, 0);
#pragma unroll
        for (int r = 0; r < 4; ++r) {
            int er = e0 + quad * 4 + r;       // C row = src-sorted edge position
            if (er < je) {
                msgf[(size_t)er * 32 + col] = acc_lo[r];
                msgf[(size_t)er * 32 + 16 + col] = acc_hi[r];
            }
        }
    }
}

// ---------- fused aggregation: root term + bias + row-gather segment-sum + relu (+ head) ----------
template <int DIN, bool HEAD>
__global__ __launch_bounds__(256) void k_agg(const float* __restrict__ xin,   // layer input (for root term)
                                             const float* __restrict__ root,  // [DIN,32]
                                             const float* __restrict__ bias,  // [32]
                                             const int* __restrict__ off_dst,
                                             const int* __restrict__ idx_dst,
                                             const float* __restrict__ msgf,
                                             const float* __restrict__ fcw,
                                             const float* __restrict__ fcb,
                                             float* __restrict__ outp) {      // aggout or logits out
    const int t = threadIdx.x;
    const int o = t & 31;
    const int n = blockIdx.x * 8 + (t >> 5);   // exactly 10000
    float s = bias[o];
#pragma unroll
    for (int i = 0; i < DIN; ++i)
        s += xin[(size_t)n * DIN + i] * root[i * 32 + o];
    int jb = off_dst[n], je = off_dst[n + 1];
    for (int j = jb; j < je; ++j) {
        int row = idx_dst[j];                  // random row, but read is one aligned 128B row
        s += msgf[(size_t)row * 32 + o];
    }
    float a = fmaxf(s, 0.f);
    if (!HEAD) {
        outp[(size_t)n * 32 + o] = a;          // stored post-relu for next layer
    } else {
        float4 p;
        p.x = a * fcw[o * 4 + 0];
        p.y = a * fcw[o * 4 + 1];
        p.z = a * fcw[o * 4 + 2];
        p.w = a * fcw[o * 4 + 3];
#pragma unroll
        for (int m = 16; m >= 1; m >>= 1) {
            p.x += __shfl_xor(p.x, m, 32);
            p.y += __shfl_xor(p.y, m, 32);
            p.z += __shfl_xor(p.z, m, 32);
            p.w += __shfl_xor(p.w, m, 32);
        }
        if (o == 0) {
            float l0 = p.x + fcb[0], l1 = p.y + fcb[1];
            float l2 = p.z + fcb[2], l3 = p.w + fcb[3];
            float mx = fmaxf(fmaxf(l0, l1), fmaxf(l2, l3));
            float sm = expf(l0 - mx) + expf(l1 - mx) + expf(l2 - mx) + expf(l3 - mx);
            float lse = mx + logf(sm);
            *(float4*)(outp + (size_t)n * 4) =
                make_float4(l0 - lse, l1 - lse, l2 - lse, l3 - lse);
        }
    }
}

extern "C" void kernel_launch(void* const* d_in, const int* in_sizes, int n_in,
                              void* d_out, int out_size, void* d_ws, size_t ws_size,
                              hipStream_t stream) {
    const float* x0 = (const float*)d_in[0];
    const int*   ei = (const int*)d_in[1];
    const float* ea = (const float*)d_in[2];
    const float *W1[3], *B1[3], *W2[3], *B2[3], *RT[3], *BS[3];
    for (int l = 0; l < 3; ++l) {
        W1[l] = (const float*)d_in[3 + 6 * l];
        B1[l] = (const float*)d_in[4 + 6 * l];
        W2[l] = (const float*)d_in[5 + 6 * l];
        B2[l] = (const float*)d_in[6 + 6 * l];
        RT[l] = (const float*)d_in[7 + 6 * l];
        BS[l] = (const float*)d_in[8 + 6 * l];
    }
    const float* fcw = (const float*)d_in[21];
    const float* fcb = (const float*)d_in[22];
    float* out = (float*)d_out;

    // ---- workspace layout ----
    int*   cnt_src = (int*)d_ws;                      // 10240
    int*   cnt_dst = cnt_src + 10240;                 // 10240 (contiguous with cnt_src for zeroing)
    int*   cur_src = cnt_dst + 10240;                 // 10240
    int*   cur_dst = cur_src + 10240;                 // 10240
    int*   off_src = cur_dst + 10240;                 // 10240 (10001 used)
    int*   off_dst = off_src + 10240;                 // 10240 (10001 used)
    int*   idx_dst = off_dst + 10240;                 // 163840 (160000 used)
    float* w2t0    = (float*)(idx_dst + 163840);      // 4096
    float* w2t1    = w2t0 + 4096;                     // 32768
    float* w2t2    = w2t1 + 32768;                    // 32768
    float* xb2     = w2t2 + 32768;                    // 320000
    float* aggA    = xb2 + 320000;                    // 320000
    float* aggB    = aggA + 320000;                   // 320000
    float* msgf    = aggB + 320000;                   // 5,120,000
    unsigned short* h0 = (unsigned short*)(msgf + 5120000);  // 5,120,000
    unsigned short* h1 = h0 + 5120000;                       // 5,120,000
    unsigned short* h2 = h1 + 5120000;                       // 5,120,000
    unsigned short* Gb = h2 + 5120000;                       // 10,240,000

    const int gE256 = (N_EDGES + 255) / 256;   // 625
    const int gG    = N_NODES / 16;            // 625
    const int gEdge = N_NODES / 4;             // 2500 (1 wave per src node)
    const int gAgg  = N_NODES / 8;             // 1250

    // ---- preprocessing (4 dispatches) ----
    k_pre0<<<352, 256, 0, stream>>>(W2[0], W2[1], W2[2], w2t0, w2t1, w2t2, cnt_src);
    k_hist<<<gE256, 256, 0, stream>>>(ei, cnt_src, cnt_dst);
    k_scan<<<2, 256, 0, stream>>>(cnt_src, cnt_dst, off_src, off_dst, cur_src, cur_dst);
    k_scatter_h<<<gE256, 256, 0, stream>>>(ei, ea, cur_src, cur_dst, idx_dst,
                                           W1[0], B1[0], W1[1], B1[1], W1[2], B1[2],
                                           h0, h1, h2);

    // ---- layer 0 (din=4) ----
    k_G<4><<<gG, 256, 0, stream>>>(x0, w2t0, B2[0], Gb, xb2);
    k_edge<<<gEdge, 256, 0, stream>>>(off_src, h0, Gb, xb2, msgf);
    k_agg<4, false><<<gAgg, 256, 0, stream>>>(x0, RT[0], BS[0], off_dst, idx_dst, msgf, fcw, fcb, aggA);

    // ---- layer 1 (din=32) ----
    k_G<32><<<gG, 256, 0, stream>>>(aggA, w2t1, B2[1], Gb, xb2);
    k_edge<<<gEdge, 256, 0, stream>>>(off_src, h1, Gb, xb2, msgf);
    k_agg<32, false><<<gAgg, 256, 0, stream>>>(aggA, RT[1], BS[1], off_dst, idx_dst, msgf, fcw, fcb, aggB);

    // ---- layer 2 (din=32) + fused head ----
    k_G<32><<<gG, 256, 0, stream>>>(aggB, w2t2, B2[2], Gb, xb2);
    k_edge<<<gEdge, 256, 0, stream>>>(off_src, h2, Gb, xb2, msgf);
    k_agg<32, true><<<gAgg, 256, 0, stream>>>(aggB, RT[2], BS[2], off_dst, idx_dst, msgf, fcw, fcb, out);
}

// Round 8
// 283.436 us; speedup vs baseline: 7.3468x; 1.0649x over previous
//
#include <hip/hip_runtime.h>
#include <hip/hip_bf16.h>
#include <math.h>

#define N_NODES 10000
#define N_EDGES 160000

typedef __attribute__((ext_vector_type(8))) short bf16x8;
typedef __attribute__((ext_vector_type(4))) float f32x4;

static __device__ inline unsigned short f2b(float v) {
    __hip_bfloat16 b = __float2bfloat16(v);
    return *reinterpret_cast<unsigned short*>(&b);
}

// ---------- zero cnt_src/cnt_dst + transpose all three w2 ----------
// w2t[i*1024 + o*32 + k] = w2[k*(din*32) + i*32 + o]
__global__ __launch_bounds__(256) void k_pre0(const float* __restrict__ s0,
                                              const float* __restrict__ s1,
                                              const float* __restrict__ s2,
                                              float* __restrict__ t0,
                                              float* __restrict__ t1,
                                              float* __restrict__ t2,
                                              int* __restrict__ cnt2) {  // cnt_src|cnt_dst, 20480 ints
    int tid = blockIdx.x * 256 + threadIdx.x;
    if (tid < 20480) { cnt2[tid] = 0; return; }
    int d = tid - 20480;
    if (d < 4096) {                            // layer 0, din=4
        int i = d >> 10, j = d & 1023, o = j >> 5, k = j & 31;
        t0[d] = s0[k * 128 + i * 32 + o];
    } else if (d < 4096 + 32768) {
        int q = d - 4096;
        int i = q >> 10, j = q & 1023, o = j >> 5, k = j & 31;
        t1[q] = s1[k * 1024 + i * 32 + o];
    } else if (d < 4096 + 65536) {
        int q = d - 4096 - 32768;
        int i = q >> 10, j = q & 1023, o = j >> 5, k = j & 31;
        t2[q] = s2[k * 1024 + i * 32 + o];
    }
}

// ---------- histograms for both src and dst ----------
__global__ __launch_bounds__(256) void k_hist(const int* __restrict__ ei,
                                              int* __restrict__ cnt_src,
                                              int* __restrict__ cnt_dst) {
    int e = blockIdx.x * 256 + threadIdx.x;
    if (e >= N_EDGES) return;
    atomicAdd(&cnt_src[ei[e]], 1);
    atomicAdd(&cnt_dst[ei[N_EDGES + e]], 1);
}

// grid=2: block 0 scans src counts, block 1 scans dst counts
__global__ __launch_bounds__(256) void k_scan(const int* __restrict__ cnt_src,
                                              const int* __restrict__ cnt_dst,
                                              int* __restrict__ off_src,
                                              int* __restrict__ off_dst,
                                              int* __restrict__ cur_src,
                                              int* __restrict__ cur_dst) {
    const int* cnt = blockIdx.x == 0 ? cnt_src : cnt_dst;
    int* off = blockIdx.x == 0 ? off_src : off_dst;
    int* cur = blockIdx.x == 0 ? cur_src : cur_dst;
    __shared__ int part[256];
    int t = threadIdx.x;
    int base = t * 40;
    int s = 0;
    for (int i = 0; i < 40; ++i) {
        int idx = base + i;
        if (idx < N_NODES) s += cnt[idx];
    }
    part[t] = s;
    __syncthreads();
    for (int d = 1; d < 256; d <<= 1) {
        int v = (t >= d) ? part[t - d] : 0;
        __syncthreads();
        part[t] += v;
        __syncthreads();
    }
    int run = part[t] - s;
    for (int i = 0; i < 40; ++i) {
        int idx = base + i;
        if (idx < N_NODES) {
            off[idx] = run;
            cur[idx] = run;
            run += cnt[idx];
        }
    }
    if (t == 255) off[N_NODES] = run;
}

// ---------- scatter edges into src-sorted order, build dst->src index, compute h (3 layers, bf16) ----------
__global__ __launch_bounds__(256) void k_scatter_h(const int* __restrict__ ei,
                                                   const float* __restrict__ ea,
                                                   int* __restrict__ cur_src,
                                                   int* __restrict__ cur_dst,
                                                   int* __restrict__ idx_dst,  // dst-sorted pos -> src-sorted pos
                                                   const float* __restrict__ w1a, const float* __restrict__ b1a,
                                                   const float* __restrict__ w1b, const float* __restrict__ b1b,
                                                   const float* __restrict__ w1c, const float* __restrict__ b1c,
                                                   unsigned short* __restrict__ h0,
                                                   unsigned short* __restrict__ h1,
                                                   unsigned short* __restrict__ h2) {
    int e = blockIdx.x * 256 + threadIdx.x;
    if (e >= N_EDGES) return;
    float a0 = ea[2 * e], a1 = ea[2 * e + 1];
    int src = ei[e], dst = ei[N_EDGES + e];
    int pos = atomicAdd(&cur_src[src], 1);
    idx_dst[atomicAdd(&cur_dst[dst], 1)] = pos;
    const float* W1[3] = {w1a, w1b, w1c};
    const float* B1[3] = {b1a, b1b, b1c};
    unsigned short* H[3] = {h0, h1, h2};
#pragma unroll
    for (int l = 0; l < 3; ++l) {
        unsigned int pk[16];
#pragma unroll
        for (int j = 0; j < 16; ++j) {
            float v0 = fmaxf(a0 * W1[l][2 * j]     + a1 * W1[l][32 + 2 * j]     + B1[l][2 * j],     0.f);
            float v1 = fmaxf(a0 * W1[l][2 * j + 1] + a1 * W1[l][32 + 2 * j + 1] + B1[l][2 * j + 1], 0.f);
            pk[j] = (unsigned int)f2b(v0) | ((unsigned int)f2b(v1) << 16);
        }
        uint4* dp = (uint4*)(H[l] + (size_t)pos * 32);
        dp[0] = make_uint4(pk[0], pk[1], pk[2], pk[3]);
        dp[1] = make_uint4(pk[4], pk[5], pk[6], pk[7]);
        dp[2] = make_uint4(pk[8], pk[9], pk[10], pk[11]);
        dp[3] = make_uint4(pk[12], pk[13], pk[14], pk[15]);
    }
}

// ---------- G[n, o*32+k] (bf16) = sum_i x[n,i]*w2t[i, o*32+k]; also xb2 (fp32) ----------
template <int DIN>
__global__ __launch_bounds__(256) void k_G(const float* __restrict__ xin,  // [N,DIN], already post-relu
                                           const float* __restrict__ w2t,  // [DIN,1024]
                                           const float* __restrict__ b2,   // [DIN*32]
                                           unsigned short* __restrict__ Gb,
                                           float* __restrict__ xb2) {
    const int t = threadIdx.x;
    const int n0 = blockIdx.x * 16;

    __shared__ float xs[16 * DIN];
    for (int idx = t; idx < 16 * DIN; idx += 256) {
        int m = idx / DIN, i = idx - m * DIN;
        xs[idx] = xin[(size_t)(n0 + m) * DIN + i];
    }
    __syncthreads();

    float acc[16][4];
#pragma unroll
    for (int m = 0; m < 16; ++m)
        acc[m][0] = acc[m][1] = acc[m][2] = acc[m][3] = 0.f;

#pragma unroll
    for (int i = 0; i < DIN; ++i) {
        const float4 w = *(const float4*)(w2t + i * 1024 + t * 4);
#pragma unroll
        for (int m = 0; m < 16; ++m) {
            float xv = xs[m * DIN + i];
            acc[m][0] += xv * w.x;
            acc[m][1] += xv * w.y;
            acc[m][2] += xv * w.z;
            acc[m][3] += xv * w.w;
        }
    }
#pragma unroll
    for (int m = 0; m < 16; ++m) {
        unsigned int p0 = (unsigned int)f2b(acc[m][0]) | ((unsigned int)f2b(acc[m][1]) << 16);
        unsigned int p1 = (unsigned int)f2b(acc[m][2]) | ((unsigned int)f2b(acc[m][3]) << 16);
        *(uint2*)(Gb + (size_t)(n0 + m) * 1024 + t * 4) = make_uint2(p0, p1);
    }

    // xb2[n,o] (512 outputs, 2 per thread)
    for (int idx = t; idx < 512; idx += 256) {
        int m = idx >> 5, o = idx & 31;
        float ab = 0.f;
#pragma unroll
        for (int i = 0; i < DIN; ++i)
            ab += xs[m * DIN + i] * b2[i * 32 + o];
        xb2[(size_t)(n0 + m) * 32 + o] = ab;
    }
}

// ---------- MFMA edge kernel: one wave per src node; CONTIGUOUS stores in src-sorted order ----------
__global__ __launch_bounds__(256) void k_edge(const int* __restrict__ off_src,
                                              const unsigned short* __restrict__ hb,
                                              const unsigned short* __restrict__ Gb,
                                              const float* __restrict__ xb2,
                                              float* __restrict__ msgf) {
    int t = threadIdx.x;
    int lane = t & 63;
    int n = blockIdx.x * 4 + (t >> 6);
    int col = lane & 15;     // C col = o (low half); A row m = edge-in-tile
    int quad = lane >> 4;    // k-block selector
    int q8 = quad * 8;

    // B frags: B[k=quad*8+j][o=col] = G_n[o*32 + k]
    const bf16x8 b_lo = *(const bf16x8*)(Gb + (size_t)n * 1024 + col * 32 + q8);
    const bf16x8 b_hi = *(const bf16x8*)(Gb + (size_t)n * 1024 + (col + 16) * 32 + q8);
    float xb_lo = xb2[(size_t)n * 32 + col];
    float xb_hi = xb2[(size_t)n * 32 + 16 + col];

    int jb = off_src[n], je = off_src[n + 1];
    for (int e0 = jb; e0 < je; e0 += 16) {
        int eA = e0 + col;
        bf16x8 afrag = {0, 0, 0, 0, 0, 0, 0, 0};
        if (eA < je) afrag = *(const bf16x8*)(hb + (size_t)eA * 32 + q8);
        f32x4 acc_lo = {xb_lo, xb_lo, xb_lo, xb_lo};
        f32x4 acc_hi = {xb_hi, xb_hi, xb_hi, xb_hi};
        acc_lo = __builtin_amdgcn_mfma_f32_16x16x32_bf16(afrag, b_lo, acc_lo, 0, 0, 0);
        acc_hi = __builtin_amdgcn_mfma_f32_16x16x32_bf16(afrag, b_hi, acc_hi, 0, 0, 0);
#pragma unroll
        for (int r = 0; r < 4; ++r) {
            int er = e0 + quad * 4 + r;       // C row = src-sorted edge position
            if (er < je) {
                msgf[(size_t)er * 32 + col] = acc_lo[r];
                msgf[(size_t)er * 32 + 16 + col] = acc_hi[r];
            }
        }
    }
}

// ---------- fused aggregation: one WAVE per dst node, 2 independent gather chains ----------
template <int DIN, bool HEAD>
__global__ __launch_bounds__(256) void k_agg(const float* __restrict__ xin,   // layer input (for root term)
                                             const float* __restrict__ root,  // [DIN,32]
                                             const float* __restrict__ bias,  // [32]
                                             const int* __restrict__ off_dst,
                                             const int* __restrict__ idx_dst,
                                             const float* __restrict__ msgf,
                                             const float* __restrict__ fcw,
                                             const float* __restrict__ fcb,
                                             float* __restrict__ outp) {      // aggout or logits out
    const int t = threadIdx.x;
    const int lane = t & 63;
    const int o = lane & 31;
    const int g = lane >> 5;                   // row-group 0/1
    const int n = blockIdx.x * 4 + (t >> 6);   // one wave per node, exactly 10000

    // root term first: independent loads issue early, overlap with gather below
    float r = bias[o];
#pragma unroll
    for (int i = 0; i < DIN; ++i)
        r += xin[(size_t)n * DIN + i] * root[i * 32 + o];

    // gather: two interleaved chains (g=0 even positions, g=1 odd), idx pipelined
    int jb = off_dst[n], je = off_dst[n + 1];
    float s = 0.f;
    int j = jb + g;
    int row_next = (j < je) ? idx_dst[j] : 0;
    for (; j < je; j += 2) {
        int row = row_next;
        int jn = j + 2;
        if (jn < je) row_next = idx_dst[jn];   // issue next idx before row load consumes
        s += msgf[(size_t)row * 32 + o];
    }
    s += __shfl_xor(s, 32);                    // combine the two row-groups (width 64)

    float a = fmaxf(s + r, 0.f);
    if (!HEAD) {
        if (g == 0) outp[(size_t)n * 32 + o] = a;   // post-relu for next layer
    } else {
        float4 p;
        p.x = a * fcw[o * 4 + 0];
        p.y = a * fcw[o * 4 + 1];
        p.z = a * fcw[o * 4 + 2];
        p.w = a * fcw[o * 4 + 3];
#pragma unroll
        for (int m = 16; m >= 1; m >>= 1) {    // reduce over o within each half-wave
            p.x += __shfl_xor(p.x, m, 32);
            p.y += __shfl_xor(p.y, m, 32);
            p.z += __shfl_xor(p.z, m, 32);
            p.w += __shfl_xor(p.w, m, 32);
        }
        if (lane == 0) {
            float l0 = p.x + fcb[0], l1 = p.y + fcb[1];
            float l2 = p.z + fcb[2], l3 = p.w + fcb[3];
            float mx = fmaxf(fmaxf(l0, l1), fmaxf(l2, l3));
            float sm = expf(l0 - mx) + expf(l1 - mx) + expf(l2 - mx) + expf(l3 - mx);
            float lse = mx + logf(sm);
            *(float4*)(outp + (size_t)n * 4) =
                make_float4(l0 - lse, l1 - lse, l2 - lse, l3 - lse);
        }
    }
}

extern "C" void kernel_launch(void* const* d_in, const int* in_sizes, int n_in,
                              void* d_out, int out_size, void* d_ws, size_t ws_size,
                              hipStream_t stream) {
    const float* x0 = (const float*)d_in[0];
    const int*   ei = (const int*)d_in[1];
    const float* ea = (const float*)d_in[2];
    const float *W1[3], *B1[3], *W2[3], *B2[3], *RT[3], *BS[3];
    for (int l = 0; l < 3; ++l) {
        W1[l] = (const float*)d_in[3 + 6 * l];
        B1[l] = (const float*)d_in[4 + 6 * l];
        W2[l] = (const float*)d_in[5 + 6 * l];
        B2[l] = (const float*)d_in[6 + 6 * l];
        RT[l] = (const float*)d_in[7 + 6 * l];
        BS[l] = (const float*)d_in[8 + 6 * l];
    }
    const float* fcw = (const float*)d_in[21];
    const float* fcb = (const float*)d_in[22];
    float* out = (float*)d_out;

    // ---- workspace layout ----
    int*   cnt_src = (int*)d_ws;                      // 10240
    int*   cnt_dst = cnt_src + 10240;                 // 10240 (contiguous with cnt_src for zeroing)
    int*   cur_src = cnt_dst + 10240;                 // 10240
    int*   cur_dst = cur_src + 10240;                 // 10240
    int*   off_src = cur_dst + 10240;                 // 10240 (10001 used)
    int*   off_dst = off_src + 10240;                 // 10240 (10001 used)
    int*   idx_dst = off_dst + 10240;                 // 163840 (160000 used)
    float* w2t0    = (float*)(idx_dst + 163840);      // 4096
    float* w2t1    = w2t0 + 4096;                     // 32768
    float* w2t2    = w2t1 + 32768;                    // 32768
    float* xb2     = w2t2 + 32768;                    // 320000
    float* aggA    = xb2 + 320000;                    // 320000
    float* aggB    = aggA + 320000;                   // 320000
    float* msgf    = aggB + 320000;                   // 5,120,000
    unsigned short* h0 = (unsigned short*)(msgf + 5120000);  // 5,120,000
    unsigned short* h1 = h0 + 5120000;                       // 5,120,000
    unsigned short* h2 = h1 + 5120000;                       // 5,120,000
    unsigned short* Gb = h2 + 5120000;                       // 10,240,000

    const int gE256 = (N_EDGES + 255) / 256;   // 625
    const int gG    = N_NODES / 16;            // 625
    const int gEdge = N_NODES / 4;             // 2500 (1 wave per src node)
    const int gAgg  = N_NODES / 4;             // 2500 (1 wave per dst node)

    // ---- preprocessing (4 dispatches) ----
    k_pre0<<<352, 256, 0, stream>>>(W2[0], W2[1], W2[2], w2t0, w2t1, w2t2, cnt_src);
    k_hist<<<gE256, 256, 0, stream>>>(ei, cnt_src, cnt_dst);
    k_scan<<<2, 256, 0, stream>>>(cnt_src, cnt_dst, off_src, off_dst, cur_src, cur_dst);
    k_scatter_h<<<gE256, 256, 0, stream>>>(ei, ea, cur_src, cur_dst, idx_dst,
                                           W1[0], B1[0], W1[1], B1[1], W1[2], B1[2],
                                           h0, h1, h2);

    // ---- layer 0 (din=4) ----
    k_G<4><<<gG, 256, 0, stream>>>(x0, w2t0, B2[0], Gb, xb2);
    k_edge<<<gEdge, 256, 0, stream>>>(off_src, h0, Gb, xb2, msgf);
    k_agg<4, false><<<gAgg, 256, 0, stream>>>(x0, RT[0], BS[0], off_dst, idx_dst, msgf, fcw, fcb, aggA);

    // ---- layer 1 (din=32) ----
    k_G<32><<<gG, 256, 0, stream>>>(aggA, w2t1, B2[1], Gb, xb2);
    k_edge<<<gEdge, 256, 0, stream>>>(off_src, h1, Gb, xb2, msgf);
    k_agg<32, false><<<gAgg, 256, 0, stream>>>(aggA, RT[1], BS[1], off_dst, idx_dst, msgf, fcw, fcb, aggB);

    // ---- layer 2 (din=32) + fused head ----
    k_G<32><<<gG, 256, 0, stream>>>(aggB, w2t2, B2[2], Gb, xb2);
    k_edge<<<gEdge, 256, 0, stream>>>(off_src, h2, Gb, xb2, msgf);
    k_agg<32, true><<<gAgg, 256, 0, stream>>>(aggB, RT[2], BS[2], off_dst, idx_dst, msgf, fcw, fcb, out);
}